// Round 3
// baseline (617.200 us; speedup 1.0000x reference)
//
#include <hip/hip_runtime.h>
#include <hip/hip_bf16.h>
#include <math.h>

#define D 128
#define GN 16    // nodes per wave-group in k_fc3
#define NBX 392  // blocks per path in k_fc3; 392*4 waves*2 groups = 3136 >= 3125

__device__ __forceinline__ float wave_sum(float v) {
#pragma unroll
  for (int off = 32; off; off >>= 1) v += __shfl_xor(v, off, 64);
  return v;
}

__device__ __forceinline__ void fma4(const float4 w, const float4 ev, float& a) {
  a = fmaf(ev.x, w.x, a);
  a = fmaf(ev.y, w.y, a);
  a = fmaf(ev.z, w.z, a);
  a = fmaf(ev.w, w.w, a);
}

// ---------------- Kernel A: intra-path attention (one wave per node) ----------------
template<int S>
__global__ __launch_bounds__(256) void k_intra(
    const float* __restrict__ h_ref, const float* __restrict__ h,
    const int* __restrict__ nei, const float* __restrict__ att,
    float* __restrict__ e_out, int N)
{
  const int wid  = threadIdx.x >> 6;
  const int lane = threadIdx.x & 63;
  const int n = blockIdx.x * 4 + wid;
  if (n >= N) return;

  const float2 aref = *(const float2*)(att + 2 * lane);
  const float2 anei = *(const float2*)(att + D + 2 * lane);
  const float2 hr   = *(const float2*)(h_ref + (size_t)n * D + 2 * lane);
  const float s_ref = wave_sum(hr.x * aref.x + hr.y * aref.y);

  const int* nrow = nei + (size_t)n * S;
  float2 nb[S];
  float  sc[S];
#pragma unroll
  for (int s = 0; s < S; ++s) {
    const int idx = nrow[s];
    nb[s] = *(const float2*)(h + (size_t)idx * D + 2 * lane);
  }
#pragma unroll
  for (int s = 0; s < S; ++s)
    sc[s] = wave_sum(nb[s].x * anei.x + nb[s].y * anei.y);

  float m = -1e30f;
#pragma unroll
  for (int s = 0; s < S; ++s) {
    float x = s_ref + sc[s];
    x = x > 0.f ? x : 0.01f * x;
    sc[s] = x;
    m = fmaxf(m, x);
  }
  float sum = 0.f;
#pragma unroll
  for (int s = 0; s < S; ++s) { sc[s] = __expf(sc[s] - m); sum += sc[s]; }
  const float inv = 1.0f / sum;

  float ex = 0.f, ey = 0.f;
#pragma unroll
  for (int s = 0; s < S; ++s) {
    const float w = sc[s] * inv;
    ex += w * nb[s].x;
    ey += w * nb[s].y;
  }
  ex = ex > 0.f ? ex : expm1f(ex);
  ey = ey > 0.f ? ey : expm1f(ey);
  *(float2*)(e_out + (size_t)n * D + 2 * lane) = make_float2(ex, ey);
}

// Generic fallback (runtime S), two-pass
__global__ __launch_bounds__(256) void k_intra_gen(
    const float* __restrict__ h_ref, const float* __restrict__ h,
    const int* __restrict__ nei, const float* __restrict__ att,
    float* __restrict__ e_out, int N, int S)
{
  const int wid  = threadIdx.x >> 6;
  const int lane = threadIdx.x & 63;
  const int n = blockIdx.x * 4 + wid;
  if (n >= N) return;
  const float2 aref = *(const float2*)(att + 2 * lane);
  const float2 anei = *(const float2*)(att + D + 2 * lane);
  const float2 hr   = *(const float2*)(h_ref + (size_t)n * D + 2 * lane);
  const float s_ref = wave_sum(hr.x * aref.x + hr.y * aref.y);
  const int* nrow = nei + (size_t)n * S;
  float m = -1e30f;
  for (int s = 0; s < S; ++s) {
    float2 v = *(const float2*)(h + (size_t)nrow[s] * D + 2 * lane);
    float x = s_ref + wave_sum(v.x * anei.x + v.y * anei.y);
    x = x > 0.f ? x : 0.01f * x;
    m = fmaxf(m, x);
  }
  float sum = 0.f, ex = 0.f, ey = 0.f;
  for (int s = 0; s < S; ++s) {
    float2 v = *(const float2*)(h + (size_t)nrow[s] * D + 2 * lane);
    float x = s_ref + wave_sum(v.x * anei.x + v.y * anei.y);
    x = x > 0.f ? x : 0.01f * x;
    float w = __expf(x - m);
    sum += w; ex += w * v.x; ey += w * v.y;
  }
  const float inv = 1.0f / sum;
  ex *= inv; ey *= inv;
  ex = ex > 0.f ? ex : expm1f(ex);
  ey = ey > 0.f ? ey : expm1f(ey);
  *(float2*)(e_out + (size_t)n * D + 2 * lane) = make_float2(ex, ey);
}

// ---------------- Kernel B (v3): tanh(e @ fcW^T + fcb), column-sum, NO atomics --------
// Lane owns j = {lane, lane+64}. Persistent: each wave grid-strides node-groups,
// accumulating post-tanh sums in registers. Block-level LDS reduction, then ONE
// non-atomic 128-float partial store per block: part[path][blockIdx.x][j].
__global__ __launch_bounds__(256) void k_fc3(
    const float* __restrict__ e1, const float* __restrict__ e2,
    const float* __restrict__ fcW, const float* __restrict__ fcb,
    float* __restrict__ part, int N)
{
  const int path = blockIdx.y;
  const float* __restrict__ e = path ? e2 : e1;
  const int lane = threadIdx.x & 63;
  const int wid  = threadIdx.x >> 6;
  const int wg   = blockIdx.x * 4 + wid;  // global wave id within path, 0..NBX*4-1

  const int j0 = lane;
  const int j1 = lane + 64;
  const float b0 = fcb[j0], b1 = fcb[j1];
  const float* __restrict__ w0p = fcW + (size_t)j0 * D;
  const float* __restrict__ w1p = fcW + (size_t)j1 * D;

  float s0 = 0.f, s1 = 0.f;

#pragma unroll 1
  for (int grp = wg; grp * GN < N; grp += NBX * 4) {
    const int n0 = __builtin_amdgcn_readfirstlane(grp * GN);

    float acc0[GN], acc1[GN];
#pragma unroll
    for (int g = 0; g < GN; ++g) { acc0[g] = b0; acc1[g] = b1; }

#pragma unroll
    for (int c = 0; c < D / 16; ++c) {
      const float4 wa0 = *(const float4*)(w0p + c * 16 + 0);
      const float4 wa1 = *(const float4*)(w0p + c * 16 + 4);
      const float4 wa2 = *(const float4*)(w0p + c * 16 + 8);
      const float4 wa3 = *(const float4*)(w0p + c * 16 + 12);
      const float4 wb0 = *(const float4*)(w1p + c * 16 + 0);
      const float4 wb1 = *(const float4*)(w1p + c * 16 + 4);
      const float4 wb2 = *(const float4*)(w1p + c * 16 + 8);
      const float4 wb3 = *(const float4*)(w1p + c * 16 + 12);
#pragma unroll
      for (int g = 0; g < GN; ++g) {
        const int n = (n0 + g < N) ? (n0 + g) : (N - 1);  // uniform clamp, in-bounds
        const float* __restrict__ er = e + (size_t)n * D + c * 16;
        const float4 ea = *(const float4*)(er + 0);
        const float4 eb = *(const float4*)(er + 4);
        const float4 ec = *(const float4*)(er + 8);
        const float4 ed = *(const float4*)(er + 12);
        fma4(wa0, ea, acc0[g]); fma4(wa1, eb, acc0[g]);
        fma4(wa2, ec, acc0[g]); fma4(wa3, ed, acc0[g]);
        fma4(wb0, ea, acc1[g]); fma4(wb1, eb, acc1[g]);
        fma4(wb2, ec, acc1[g]); fma4(wb3, ed, acc1[g]);
      }
    }

#pragma unroll
    for (int g = 0; g < GN; ++g) {
      if (n0 + g < N) {
        s0 += tanhf(acc0[g]);
        s1 += tanhf(acc1[g]);
      }
    }
  }

  // Block reduction across 4 waves (all waves own the same j set), one store.
  __shared__ float sd[4][D];
  sd[wid][j0] = s0;
  sd[wid][j1] = s1;
  __syncthreads();
  if (threadIdx.x < D) {
    const float v = sd[0][threadIdx.x] + sd[1][threadIdx.x] +
                    sd[2][threadIdx.x] + sd[3][threadIdx.x];
    part[((size_t)path * NBX + blockIdx.x) * D + threadIdx.x] = v;
  }
}

// ---------------- Kernel C: reduce partials -> sps -> beta (one block) ----------------
__global__ __launch_bounds__(256) void k_finish(
    const float* __restrict__ part, const float* __restrict__ att_inter,
    float* __restrict__ beta, float invN)
{
  const int t    = threadIdx.x;
  const int path = t >> 7;
  const int j    = t & 127;
  const int lane = t & 63;
  const int wid  = t >> 6;

  const float* __restrict__ p = part + (size_t)path * NBX * D + j;
  float s = 0.f;
#pragma unroll 4
  for (int b = 0; b < NBX; ++b) s += p[(size_t)b * D];

  float v = (s * invN) * att_inter[j];
  v = wave_sum(v);

  __shared__ float red[4];
  if (lane == 0) red[wid] = v;
  __syncthreads();
  if (t == 0) {
    const float v0 = red[0] + red[1];
    const float v1 = red[2] + red[3];
    const float m = fmaxf(v0, v1);
    const float p0 = __expf(v0 - m), p1 = __expf(v1 - m);
    const float inv = 1.f / (p0 + p1);
    beta[0] = p0 * inv;
    beta[1] = p1 * inv;
  }
}

// ---------------- Kernel D: out = b0*e1 + b1*e2 ----------------
__global__ __launch_bounds__(256) void k_combine(
    const float* __restrict__ e1, const float* __restrict__ e2,
    const float* __restrict__ beta, float* __restrict__ out, int total4)
{
  const float b0 = beta[0], b1 = beta[1];
  const float4* p1 = (const float4*)e1;
  const float4* p2 = (const float4*)e2;
  float4* po = (float4*)out;
  int i = blockIdx.x * 256 + threadIdx.x;
  const int stride = gridDim.x * 256;
  for (; i < total4; i += stride) {
    const float4 a = p1[i], b = p2[i];
    po[i] = make_float4(b0 * a.x + b1 * b.x, b0 * a.y + b1 * b.y,
                        b0 * a.z + b1 * b.z, b0 * a.w + b1 * b.w);
  }
}

extern "C" void kernel_launch(void* const* d_in, const int* in_sizes, int n_in,
                              void* d_out, int out_size, void* d_ws, size_t ws_size,
                              hipStream_t stream) {
  const float* h_ref     = (const float*)d_in[0];
  const float* h1        = (const float*)d_in[1];
  const float* h2        = (const float*)d_in[2];
  const int*   nei1      = (const int*)d_in[3];
  const int*   nei2      = (const int*)d_in[4];
  const float* att1      = (const float*)d_in[5];
  const float* att2      = (const float*)d_in[6];
  const float* fcW       = (const float*)d_in[7];
  const float* fcb       = (const float*)d_in[8];
  const float* att_inter = (const float*)d_in[9];

  const int N  = in_sizes[0] / D;
  const int S1 = in_sizes[3] / N;
  const int S2 = in_sizes[4] / N;

  float* e1   = (float*)d_ws;
  float* e2   = e1 + (size_t)N * D;
  float* part = e2 + (size_t)N * D;          // 2 * NBX * D floats
  float* beta = part + (size_t)2 * NBX * D;  // 2 floats
  float* out  = (float*)d_out;

  const dim3 gA((N + 3) / 4);
  if (S1 == 20)      k_intra<20><<<gA, 256, 0, stream>>>(h_ref, h1, nei1, att1, e1, N);
  else if (S1 == 10) k_intra<10><<<gA, 256, 0, stream>>>(h_ref, h1, nei1, att1, e1, N);
  else               k_intra_gen<<<gA, 256, 0, stream>>>(h_ref, h1, nei1, att1, e1, N, S1);

  if (S2 == 10)      k_intra<10><<<gA, 256, 0, stream>>>(h_ref, h2, nei2, att2, e2, N);
  else if (S2 == 20) k_intra<20><<<gA, 256, 0, stream>>>(h_ref, h2, nei2, att2, e2, N);
  else               k_intra_gen<<<gA, 256, 0, stream>>>(h_ref, h2, nei2, att2, e2, N, S2);

  const dim3 gB(NBX, 2);
  k_fc3<<<gB, 256, 0, stream>>>(e1, e2, fcW, fcb, part, N);

  k_finish<<<1, 256, 0, stream>>>(part, att_inter, beta, 1.0f / (float)N);

  const int total4 = N * D / 4;
  int gD = (total4 + 255) / 256;
  if (gD > 2048) gD = 2048;
  k_combine<<<gD, 256, 0, stream>>>(e1, e2, beta, out, total4);
}

// Round 5
// 179.911 us; speedup vs baseline: 3.4306x; 3.4306x over previous
//
#include <hip/hip_runtime.h>
#include <hip/hip_bf16.h>
#include <math.h>

#define D 128
#define NB2 96            // blocks per path in k_fc5
#define NWAVES (NB2 * 4)  // waves per path

typedef __attribute__((ext_vector_type(8))) short bf16x8;
typedef __attribute__((ext_vector_type(4))) float f32x4;

__device__ __forceinline__ float wave_sum(float v) {
#pragma unroll
  for (int off = 32; off; off >>= 1) v += __shfl_xor(v, off, 64);
  return v;
}

// fp32 -> bf16 round-to-nearest-even (finite inputs)
__device__ __forceinline__ unsigned bfr(float f) {
  const unsigned u = __float_as_uint(f);
  return (u + 0x7FFFu + ((u >> 16) & 1u)) >> 16;
}

// ---------------- Kernel A: intra-path attention (one wave per node), bf16 out -------
template<int S>
__global__ __launch_bounds__(256) void k_intra(
    const float* __restrict__ h_ref, const float* __restrict__ h,
    const int* __restrict__ nei, const float* __restrict__ att,
    unsigned* __restrict__ eb, int N)  // eb: bf16[N][D] viewed as dwords
{
  const int wid  = threadIdx.x >> 6;
  const int lane = threadIdx.x & 63;
  const int n = blockIdx.x * 4 + wid;
  if (n >= N) return;

  const float2 aref = *(const float2*)(att + 2 * lane);
  const float2 anei = *(const float2*)(att + D + 2 * lane);
  const float2 hr   = *(const float2*)(h_ref + (size_t)n * D + 2 * lane);
  const float s_ref = wave_sum(hr.x * aref.x + hr.y * aref.y);

  const int* nrow = nei + (size_t)n * S;
  float2 nb[S];
  float  sc[S];
#pragma unroll
  for (int s = 0; s < S; ++s) {
    const int idx = nrow[s];
    nb[s] = *(const float2*)(h + (size_t)idx * D + 2 * lane);
  }
#pragma unroll
  for (int s = 0; s < S; ++s)
    sc[s] = wave_sum(nb[s].x * anei.x + nb[s].y * anei.y);

  float m = -1e30f;
#pragma unroll
  for (int s = 0; s < S; ++s) {
    float x = s_ref + sc[s];
    x = x > 0.f ? x : 0.01f * x;
    sc[s] = x;
    m = fmaxf(m, x);
  }
  float sum = 0.f;
#pragma unroll
  for (int s = 0; s < S; ++s) { sc[s] = __expf(sc[s] - m); sum += sc[s]; }
  const float inv = 1.0f / sum;

  float ex = 0.f, ey = 0.f;
#pragma unroll
  for (int s = 0; s < S; ++s) {
    const float w = sc[s] * inv;
    ex += w * nb[s].x;
    ey += w * nb[s].y;
  }
  ex = ex > 0.f ? ex : expm1f(ex);
  ey = ey > 0.f ? ey : expm1f(ey);
  eb[(size_t)n * (D / 2) + lane] = (bfr(ey) << 16) | bfr(ex);
}

// Generic fallback (runtime S), two-pass
__global__ __launch_bounds__(256) void k_intra_gen(
    const float* __restrict__ h_ref, const float* __restrict__ h,
    const int* __restrict__ nei, const float* __restrict__ att,
    unsigned* __restrict__ eb, int N, int S)
{
  const int wid  = threadIdx.x >> 6;
  const int lane = threadIdx.x & 63;
  const int n = blockIdx.x * 4 + wid;
  if (n >= N) return;
  const float2 aref = *(const float2*)(att + 2 * lane);
  const float2 anei = *(const float2*)(att + D + 2 * lane);
  const float2 hr   = *(const float2*)(h_ref + (size_t)n * D + 2 * lane);
  const float s_ref = wave_sum(hr.x * aref.x + hr.y * aref.y);
  const int* nrow = nei + (size_t)n * S;
  float m = -1e30f;
  for (int s = 0; s < S; ++s) {
    float2 v = *(const float2*)(h + (size_t)nrow[s] * D + 2 * lane);
    float x = s_ref + wave_sum(v.x * anei.x + v.y * anei.y);
    x = x > 0.f ? x : 0.01f * x;
    m = fmaxf(m, x);
  }
  float sum = 0.f, ex = 0.f, ey = 0.f;
  for (int s = 0; s < S; ++s) {
    float2 v = *(const float2*)(h + (size_t)nrow[s] * D + 2 * lane);
    float x = s_ref + wave_sum(v.x * anei.x + v.y * anei.y);
    x = x > 0.f ? x : 0.01f * x;
    float w = __expf(x - m);
    sum += w; ex += w * v.x; ey += w * v.y;
  }
  const float inv = 1.0f / sum;
  ex *= inv; ey *= inv;
  ex = ex > 0.f ? ex : expm1f(ex);
  ey = ey > 0.f ? ey : expm1f(ey);
  eb[(size_t)n * (D / 2) + lane] = (bfr(ey) << 16) | bfr(ex);
}

// ---------------- Kernel P: fcW fp32 -> bf16 ----------------
__global__ __launch_bounds__(256) void k_prep(
    const float* __restrict__ w, unsigned short* __restrict__ wb, int n)
{
  const int i = blockIdx.x * 256 + threadIdx.x;
  if (i < n) wb[i] = (unsigned short)bfr(w[i]);
}

// ---------------- Kernel B (v5): MFMA GEMM, tanh epilogue, column-sum partials -------
// Wave owns a 16-node strip. B = whole 128x128 W in registers (8 jt x 4 kc frags).
// A-frag: lane holds row n0+(lane&15), k = kc*32 + (lane>>4)*8 + 0..7 (16B load).
// C/D mapping (verified): col j2 = lane&15, row = (lane>>4)*4 + q.
__global__ __launch_bounds__(256) void k_fc5(
    const unsigned short* __restrict__ eb1, const unsigned short* __restrict__ eb2,
    const unsigned short* __restrict__ wb, const float* __restrict__ fcb,
    float* __restrict__ part, int N)
{
  const int path = blockIdx.y;
  const unsigned short* __restrict__ eb = path ? eb2 : eb1;
  const int lane = threadIdx.x & 63;
  const int wave = blockIdx.x * 4 + (threadIdx.x >> 6);
  const int r  = lane & 15;
  const int hi = lane >> 4;

  bf16x8 B[8][4];
#pragma unroll
  for (int jt = 0; jt < 8; ++jt)
#pragma unroll
    for (int kc = 0; kc < 4; ++kc)
      B[jt][kc] = *(const bf16x8*)(wb + (size_t)(jt * 16 + r) * D + kc * 32 + hi * 8);

  float bias[8];
#pragma unroll
  for (int jt = 0; jt < 8; ++jt) bias[jt] = fcb[jt * 16 + r];

  float wsum[8];
#pragma unroll
  for (int jt = 0; jt < 8; ++jt) wsum[jt] = 0.f;

  const int nstrips = (N + 15) / 16;
  for (int st = wave; st < nstrips; st += NWAVES) {
    const int n0 = st * 16;
    int na = n0 + r;
    if (na >= N) na = N - 1;  // clamp keeps loads in-bounds; masked in epilogue
    const unsigned short* arow = eb + (size_t)na * D + hi * 8;
    bf16x8 A[4];
#pragma unroll
    for (int kc = 0; kc < 4; ++kc) A[kc] = *(const bf16x8*)(arow + kc * 32);

    f32x4 acc[8];
#pragma unroll
    for (int jt = 0; jt < 8; ++jt) acc[jt] = (f32x4){0.f, 0.f, 0.f, 0.f};
#pragma unroll
    for (int kc = 0; kc < 4; ++kc)
#pragma unroll
      for (int jt = 0; jt < 8; ++jt)
        acc[jt] = __builtin_amdgcn_mfma_f32_16x16x32_bf16(A[kc], B[jt][kc], acc[jt], 0, 0, 0);

#pragma unroll
    for (int jt = 0; jt < 8; ++jt) {
      float s = 0.f;
#pragma unroll
      for (int q = 0; q < 4; ++q) {
        const int node = n0 + hi * 4 + q;
        const float t = tanhf(acc[jt][q] + bias[jt]);
        s += (node < N) ? t : 0.f;
      }
      s += __shfl_xor(s, 16, 64);
      s += __shfl_xor(s, 32, 64);
      wsum[jt] += s;
    }
  }

  if (lane < 16) {
    float* p = part + ((size_t)path * NWAVES + wave) * D;
#pragma unroll
    for (int jt = 0; jt < 8; ++jt) p[jt * 16 + lane] = wsum[jt];
  }
}

// ---------------- Kernel C: reduce partials -> sps -> beta (one block) ----------------
__global__ __launch_bounds__(256) void k_finish(
    const float* __restrict__ part, const float* __restrict__ att_inter,
    float* __restrict__ beta, float invN)
{
  const int t    = threadIdx.x;
  const int path = t >> 7;
  const int j    = t & 127;
  const int lane = t & 63;
  const int wid  = t >> 6;

  const float* __restrict__ p = part + (size_t)path * NWAVES * D + j;
  float s = 0.f;
#pragma unroll 8
  for (int w = 0; w < NWAVES; ++w) s += p[(size_t)w * D];

  float v = (s * invN) * att_inter[j];
  v = wave_sum(v);

  __shared__ float red[4];
  if (lane == 0) red[wid] = v;
  __syncthreads();
  if (t == 0) {
    const float v0 = red[0] + red[1];
    const float v1 = red[2] + red[3];
    const float m = fmaxf(v0, v1);
    const float p0 = __expf(v0 - m), p1 = __expf(v1 - m);
    const float inv = 1.f / (p0 + p1);
    beta[0] = p0 * inv;
    beta[1] = p1 * inv;
  }
}

// ---------------- Kernel D: out = b0*e1 + b1*e2 (bf16 sources, fp32 out) -------------
__global__ __launch_bounds__(256) void k_combine(
    const uint2* __restrict__ eb1v, const uint2* __restrict__ eb2v,
    const float* __restrict__ beta, float* __restrict__ outp, int total4)
{
  const float b0 = beta[0], b1 = beta[1];
  float4* out = (float4*)outp;
  int i = blockIdx.x * 256 + threadIdx.x;
  const int stride = gridDim.x * 256;
  for (; i < total4; i += stride) {
    const uint2 a = eb1v[i], b = eb2v[i];
    float4 o;
    o.x = b0 * __uint_as_float(a.x << 16)         + b1 * __uint_as_float(b.x << 16);
    o.y = b0 * __uint_as_float(a.x & 0xFFFF0000u) + b1 * __uint_as_float(b.x & 0xFFFF0000u);
    o.z = b0 * __uint_as_float(a.y << 16)         + b1 * __uint_as_float(b.y << 16);
    o.w = b0 * __uint_as_float(a.y & 0xFFFF0000u) + b1 * __uint_as_float(b.y & 0xFFFF0000u);
    out[i] = o;
  }
}

extern "C" void kernel_launch(void* const* d_in, const int* in_sizes, int n_in,
                              void* d_out, int out_size, void* d_ws, size_t ws_size,
                              hipStream_t stream) {
  const float* h_ref     = (const float*)d_in[0];
  const float* h1        = (const float*)d_in[1];
  const float* h2        = (const float*)d_in[2];
  const int*   nei1      = (const int*)d_in[3];
  const int*   nei2      = (const int*)d_in[4];
  const float* att1      = (const float*)d_in[5];
  const float* att2      = (const float*)d_in[6];
  const float* fcW       = (const float*)d_in[7];
  const float* fcb       = (const float*)d_in[8];
  const float* att_inter = (const float*)d_in[9];

  const int N  = in_sizes[0] / D;
  const int S1 = in_sizes[3] / N;
  const int S2 = in_sizes[4] / N;

  unsigned short* eb1 = (unsigned short*)d_ws;                 // bf16 e1 [N][D]
  unsigned short* eb2 = eb1 + (size_t)N * D;                   // bf16 e2 [N][D]
  unsigned short* wb  = eb2 + (size_t)N * D;                   // bf16 W  [D][D]
  float* part = (float*)(wb + D * D);                          // [2][NWAVES][D]
  float* beta = part + (size_t)2 * NWAVES * D;                 // 2 floats
  float* out  = (float*)d_out;

  k_prep<<<(D * D + 255) / 256, 256, 0, stream>>>(fcW, wb, D * D);

  const dim3 gA((N + 3) / 4);
  if (S1 == 20)      k_intra<20><<<gA, 256, 0, stream>>>(h_ref, h1, nei1, att1, (unsigned*)eb1, N);
  else if (S1 == 10) k_intra<10><<<gA, 256, 0, stream>>>(h_ref, h1, nei1, att1, (unsigned*)eb1, N);
  else               k_intra_gen<<<gA, 256, 0, stream>>>(h_ref, h1, nei1, att1, (unsigned*)eb1, N, S1);

  if (S2 == 10)      k_intra<10><<<gA, 256, 0, stream>>>(h_ref, h2, nei2, att2, (unsigned*)eb2, N);
  else if (S2 == 20) k_intra<20><<<gA, 256, 0, stream>>>(h_ref, h2, nei2, att2, (unsigned*)eb2, N);
  else               k_intra_gen<<<gA, 256, 0, stream>>>(h_ref, h2, nei2, att2, (unsigned*)eb2, N, S2);

  const dim3 gB(NB2, 2);
  k_fc5<<<gB, 256, 0, stream>>>(eb1, eb2, wb, fcb, part, N);

  k_finish<<<1, 256, 0, stream>>>(part, att_inter, beta, 1.0f / (float)N);

  const int total4 = N * D / 4;
  int gD = (total4 + 255) / 256;
  if (gD > 2048) gD = 2048;
  k_combine<<<gD, 256, 0, stream>>>((const uint2*)eb1, (const uint2*)eb2, beta, out, total4);
}